// Round 16
// baseline (302.111 us; speedup 1.0000x reference)
//
#include <hip/hip_runtime.h>
#include <hip/hip_bf16.h>

typedef __attribute__((ext_vector_type(8))) __bf16 bf16x8;
typedef __attribute__((ext_vector_type(4))) __bf16 bf16x4;
typedef __attribute__((ext_vector_type(4))) float f32x4;

#define B_ROWS 16384
#define LDF 2560
#define BN_EPS 1e-5f

__device__ __forceinline__ void async16(void* lds, const void* g) {
  __builtin_amdgcn_global_load_lds(
      (const __attribute__((address_space(1))) unsigned int*)g,
      (__attribute__((address_space(3))) unsigned int*)lds, 16, 0, 0);
}

__device__ __forceinline__ bf16x8 cvt8(float4 a, float4 b) {
  bf16x8 t;
  t[0] = (__bf16)a.x; t[1] = (__bf16)a.y; t[2] = (__bf16)a.z; t[3] = (__bf16)a.w;
  t[4] = (__bf16)b.x; t[5] = (__bf16)b.y; t[6] = (__bf16)b.z; t[7] = (__bf16)b.w;
  return t;
}

// C-tile = A(bf16,[B_ROWS,LDF]) x W(bf16,[Ntot,Kd])^T (+badj in epilogue)
// BM=128 x BN=128, BK=64, 512 threads = 8 waves (4wm x 2wn), wave-tile 32x64,
// acc 2x4. LDS-traffic-optimal wave split: reads BK*2*(BM*2 + BN*4)... = 96KB +
// 32KB writes per block-iter for 2.1 MFLOP (vs R15 176KB/2.1M at 2 blocks).
// 3-buffer LDS (96KB -> 1 block/CU, 8 waves), prefetch depth 2.
// STAGE = 4 gload_lds/thread; loop top has tiles t,t+1 in flight (8 loads);
// vmcnt(4) completes exactly tile t. Tile t+2 -> buf (rb+2)%3 (no overlap).
// LDS row = 64 elems (8 slots of 8); slot holds k-chunk (slot ^ (row&7)) via
// pre-swizzled source; read slot = kc ^ (row&7) -> 2 lanes/bank (free).
// Grid 1-D, XCD-chunked swizzle (gridDim%8==0): wgid -> (bx, by).
// mode 1: h=relu(acc+badj) -> bf16 hout (stride LDF) + col stats atomics.
// mode 0: fp32 out = acc + badj (ldc=128), direct.
__global__ __launch_bounds__(512) void gemm_stage(
    const __bf16* __restrict__ A, const __bf16* __restrict__ W,
    const float* __restrict__ badj,
    __bf16* __restrict__ hout, float* __restrict__ fout,
    float* __restrict__ colsum, float* __restrict__ colsumsq,
    int Kd, int mode, int bxbits)
{
  __shared__ __bf16 lds[3][16384];  // per buf: A 128x64 (8192) + B 128x64 (8192)

  const int tid  = threadIdx.x;
  const int lane = tid & 63;
  const int wid  = tid >> 6;         // 0..7
  const int wm   = wid >> 1, wn = wid & 1;
  const int fr   = lane & 15, fk = lane >> 4;

  const int cpx  = gridDim.x >> 3;
  const int wgid = (blockIdx.x & 7) * cpx + (blockIdx.x >> 3);
  const int bx   = wgid & ((1 << bxbits) - 1);
  const int by   = wgid >> bxbits;
  const int bn0  = bx * 128, bm0 = by * 128;

  // staging: chunk c = j*512+tid (j=0,1): row = j*64 + (tid>>3), slot = tid&7.
  // Source k-chunk pre-swizzled: ko = slot ^ (row&7)  ((row&7) same for both j).
  const int srow = tid >> 3;
  const int sko  = ((tid & 7) ^ (srow & 7)) << 3;  // elems
  const __bf16* a0p = A + (size_t)(bm0 + srow) * LDF + sko;
  const __bf16* a1p = a0p + (size_t)64 * LDF;
  const __bf16* b0p = W + (size_t)(bn0 + srow) * Kd + sko;
  const __bf16* b1p = b0p + (size_t)64 * Kd;

#define STAGE(b, kt) do {                                                  \
    async16((void*)(&lds[b][(size_t)tid * 8]),                a0p + (kt)); \
    async16((void*)(&lds[b][(size_t)(512 + tid) * 8]),        a1p + (kt)); \
    async16((void*)(&lds[b][(size_t)(1024 + tid) * 8]),       b0p + (kt)); \
    async16((void*)(&lds[b][(size_t)(1536 + tid) * 8]),       b1p + (kt)); \
  } while (0)

  // fragment read offsets (loop-invariant): elem = r*64 + ((kc ^ (r&7))<<3)
  int aoff[2][2], boff[2][4];
#pragma unroll
  for (int ksub = 0; ksub < 2; ++ksub) {
    const int kc = ksub * 4 + fk;
#pragma unroll
    for (int i = 0; i < 2; ++i) {
      int ra = wm * 32 + i * 16 + fr;
      aoff[ksub][i] = ra * 64 + ((kc ^ (ra & 7)) << 3);
    }
#pragma unroll
    for (int i = 0; i < 4; ++i) {
      int rb2 = wn * 64 + i * 16 + fr;
      boff[ksub][i] = 8192 + rb2 * 64 + ((kc ^ (rb2 & 7)) << 3);
    }
  }

  f32x4 acc[2][4] = {};

  const int NT = Kd >> 6;
  STAGE(0, 0);
  STAGE(1, 64);

  int rb = 0;
  for (int t = 0; t < NT; ++t) {
    if (t < NT - 1) asm volatile("s_waitcnt vmcnt(4)" ::: "memory");
    else            asm volatile("s_waitcnt vmcnt(0)" ::: "memory");
    __builtin_amdgcn_s_barrier();
    __builtin_amdgcn_sched_barrier(0);

    if (t + 2 < NT) {
      int sb = rb + 2; if (sb >= 3) sb -= 3;
      STAGE(sb, (t + 2) * 64);
    }
    __builtin_amdgcn_sched_barrier(0);

    const __bf16* bp = lds[rb];
    __builtin_amdgcn_s_setprio(1);
#pragma unroll
    for (int ksub = 0; ksub < 2; ++ksub) {
      bf16x8 af[2], bf[4];
#pragma unroll
      for (int i = 0; i < 2; ++i) af[i] = *(const bf16x8*)(bp + aoff[ksub][i]);
#pragma unroll
      for (int i = 0; i < 4; ++i) bf[i] = *(const bf16x8*)(bp + boff[ksub][i]);
#pragma unroll
      for (int mi = 0; mi < 2; ++mi)
#pragma unroll
        for (int ni = 0; ni < 4; ++ni)
          acc[mi][ni] = __builtin_amdgcn_mfma_f32_16x16x32_bf16(af[mi], bf[ni], acc[mi][ni], 0, 0, 0);
    }
    __builtin_amdgcn_s_setprio(0);

    if (++rb == 3) rb = 0;
  }
#undef STAGE

  if (mode) {
    float psum[4] = {0.f, 0.f, 0.f, 0.f}, psq[4] = {0.f, 0.f, 0.f, 0.f};
#pragma unroll
    for (int mi = 0; mi < 2; ++mi) {
#pragma unroll
      for (int ni = 0; ni < 4; ++ni) {
        const int col  = bn0 + wn * 64 + ni * 16 + fr;
        const int row0 = bm0 + wm * 32 + mi * 16 + fk * 4;
        const float bv = badj[col];
        __bf16* hp = hout + (size_t)row0 * LDF + col;
#pragma unroll
        for (int r = 0; r < 4; ++r) {
          float v = fmaxf(acc[mi][ni][r] + bv, 0.f);
          psum[ni] += v; psq[ni] += v * v;
          hp[(size_t)r * LDF] = (__bf16)v;
        }
      }
    }
#pragma unroll
    for (int ni = 0; ni < 4; ++ni) {
      float s = psum[ni], q = psq[ni];
      s += __shfl_xor(s, 16); s += __shfl_xor(s, 32);
      q += __shfl_xor(q, 16); q += __shfl_xor(q, 32);
      if (fk == 0) {
        int col = bn0 + wn * 64 + ni * 16 + fr;
        atomicAdd(&colsum[col], s);
        atomicAdd(&colsumsq[col], q);
      }
    }
  } else {
#pragma unroll
    for (int mi = 0; mi < 2; ++mi) {
#pragma unroll
      for (int ni = 0; ni < 4; ++ni) {
        const int col  = bn0 + wn * 64 + ni * 16 + fr;
        const int row0 = bm0 + wm * 32 + mi * 16 + fk * 4;
        const float bv = badj[col];
        float* cp = fout + (size_t)row0 * 128 + col;
#pragma unroll
        for (int r = 0; r < 4; ++r)
          cp[(size_t)r * 128] = acc[mi][ni][r] + bv;
      }
    }
  }
}

__global__ void cast_x_kernel(const float* __restrict__ x, __bf16* __restrict__ feats) {
  int idx = blockIdx.x * blockDim.x + threadIdx.x;  // B_ROWS*64 threads
  int row = idx >> 6, c8 = (idx & 63) << 3;
  const float4* xp = (const float4*)(x + (size_t)row * 512 + c8);
  float4 a = xp[0], b = xp[1];
  *(bf16x8*)(feats + (size_t)row * LDF + c8) = cvt8(a, b);
}

// Fused fp32->bf16 W-cast with BN folded: W'[n,c]=W[n,c]*sc[c]; badj[n]=bias[n]+sum_c sh[c]*W[n,c]
// Also zeroes this stage's colsum/colsumsq slice (256 entries) if zs/zq given.
__global__ void prep_w(const float* __restrict__ W, const float* __restrict__ bias,
                       const float* __restrict__ colsum, const float* __restrict__ colsumsq,
                       const float* __restrict__ gamma, const float* __restrict__ beta,
                       __bf16* __restrict__ Wb, float* __restrict__ badj, int Kd,
                       float* __restrict__ zs, float* __restrict__ zq)
{
  const int n = blockIdx.x, t = threadIdx.x;  // 256 threads per row
  if (zs && t == 0 && n < 256) { zs[n] = 0.f; zq[n] = 0.f; }
  const float invB = 1.0f / 16384.0f;
  float accb = 0.f;
  for (int c0 = t * 4; c0 < Kd; c0 += 1024) {
    float4 w = *(const float4*)(W + (size_t)n * Kd + c0);
    float wv[4] = {w.x, w.y, w.z, w.w};
    bf16x4 o;
#pragma unroll
    for (int i = 0; i < 4; ++i) {
      int c = c0 + i;
      float sc = 1.f, sh = 0.f;
      if (c >= 512) {
        int idx = c - 512;
        float mu  = colsum[idx] * invB;
        float var = colsumsq[idx] * invB - mu * mu;
        sc = gamma[idx] * rsqrtf(var + BN_EPS);
        sh = beta[idx] - mu * sc;
      }
      accb += wv[i] * sh;
      o[i] = (__bf16)(wv[i] * sc);
    }
    *(bf16x4*)(Wb + (size_t)n * Kd + c0) = o;
  }
  __shared__ float red[256];
  red[t] = accb;
  __syncthreads();
  for (int s = 128; s > 0; s >>= 1) {
    if (t < s) red[t] += red[t + s];
    __syncthreads();
  }
  if (t == 0) badj[n] = bias[n] + red[0];
}

extern "C" void kernel_launch(void* const* d_in, const int* in_sizes, int n_in,
                              void* d_out, int out_size, void* d_ws, size_t ws_size,
                              hipStream_t stream) {
  const float* x = (const float*)d_in[0];
  const float* Wi[8];
  for (int i = 0; i < 8; ++i) Wi[i] = (const float*)d_in[1 + i];
  const float* b     = (const float*)d_in[9];
  const float* gamma = (const float*)d_in[10];
  const float* beta  = (const float*)d_in[11];
  const float* Wout  = (const float*)d_in[12];
  const float* bout  = (const float*)d_in[13];
  float* out = (float*)d_out;

  char* ws = (char*)d_ws;
  __bf16* feats = (__bf16*)ws;
  size_t off = (size_t)B_ROWS * LDF * 2;
  __bf16* wb[8];
  {
    int d = 512;
    for (int i = 0; i < 8; ++i) { wb[i] = (__bf16*)(ws + off); off += (size_t)256 * d * 2; d += 256; }
  }
  __bf16* woutb = (__bf16*)(ws + off); off += (size_t)128 * 2560 * 2;
  float* colsum   = (float*)(ws + off); off += 8 * 256 * 4;
  float* colsumsq = (float*)(ws + off); off += 8 * 256 * 4;
  float* badj     = (float*)(ws + off); off += 9 * 256 * 4;

  cast_x_kernel<<<B_ROWS * 64 / 256, 256, 0, stream>>>(x, feats);

  int d = 512;
  for (int i = 0; i < 8; ++i) {
    prep_w<<<256, 256, 0, stream>>>(Wi[i], b + i * 256, colsum, colsumsq,
                                    gamma, beta, wb[i], badj + i * 256, d,
                                    colsum + i * 256, colsumsq + i * 256);
    // grid = 2 bx * 128 by = 256 blocks of 512 threads (1 block/CU, 8 waves)
    gemm_stage<<<256, 512, 0, stream>>>(feats, wb[i], badj + i * 256,
                                        feats + d, nullptr,
                                        colsum + i * 256, colsumsq + i * 256,
                                        d, 1, 1);
    d += 256;
  }
  prep_w<<<128, 256, 0, stream>>>(Wout, bout, colsum, colsumsq,
                                  gamma, beta, woutb, badj + 8 * 256, 2560,
                                  nullptr, nullptr);
  // final: direct, grid = 1 bx * 128 by = 128 blocks, NT=40
  gemm_stage<<<128, 512, 0, stream>>>(feats, woutb, badj + 8 * 256,
                                      nullptr, out, nullptr, nullptr,
                                      2560, 0, 0);
}

// Round 17
// 282.080 us; speedup vs baseline: 1.0710x; 1.0710x over previous
//
#include <hip/hip_runtime.h>
#include <hip/hip_bf16.h>

typedef __attribute__((ext_vector_type(8))) __bf16 bf16x8;
typedef __attribute__((ext_vector_type(4))) __bf16 bf16x4;
typedef __attribute__((ext_vector_type(4))) float f32x4;

#define B_ROWS 16384
#define LDF 2560
#define BN_EPS 1e-5f

__device__ __forceinline__ void async16(void* lds, const void* g) {
  __builtin_amdgcn_global_load_lds(
      (const __attribute__((address_space(1))) unsigned int*)g,
      (__attribute__((address_space(3))) unsigned int*)lds, 16, 0, 0);
}

__device__ __forceinline__ bf16x8 cvt8(float4 a, float4 b) {
  bf16x8 t;
  t[0] = (__bf16)a.x; t[1] = (__bf16)a.y; t[2] = (__bf16)a.z; t[3] = (__bf16)a.w;
  t[4] = (__bf16)b.x; t[5] = (__bf16)b.y; t[6] = (__bf16)b.z; t[7] = (__bf16)b.w;
  return t;
}

// C-tile = A(bf16,[B_ROWS,LDF]) x W(bf16,[Ntot,Kd])^T (+badj in epilogue)
// BM=64 x BN=128, BK=64, 512 threads = 8 waves (2wm x 4wn), wave-tile 32x32,
// acc 2x2. 16 waves/CU at 2 blocks/CU (72KB LDS). [R13/R15-verified structure;
// stage-7 time == LDS-pipe floor: 2 blk x 88KB/iter / 128 B/cyc x NT=36]
// 3-buffer LDS, prefetch depth 2. STAGE = 3 gload_lds/thread; loop top has
// tiles t,t+1 in flight (6/thread); vmcnt(3) completes exactly tile t.
// LDS row = 64 elems (8 slots of 8); slot holds k-chunk (slot ^ (row&7)) via
// pre-swizzled source; read slot = kc ^ (row&7) -> 2 lanes/bank (free).
// Grid 1-D, XCD-chunked swizzle (gridDim%8==0): wgid -> (bx, by).
// mode 1: h=relu(acc+badj) -> bf16 hout (stride LDF) + col stats atomics.
// mode 0: fp32 out = acc + badj (ldc=128), direct (no split-K).
// [R17 A/B: s_setprio removed — lockstep barrier loop, T5 predicted null/neg]
__global__ __launch_bounds__(512) void gemm_stage(
    const __bf16* __restrict__ A, const __bf16* __restrict__ W,
    const float* __restrict__ badj,
    __bf16* __restrict__ hout, float* __restrict__ fout,
    float* __restrict__ colsum, float* __restrict__ colsumsq,
    int Kd, int mode, int bxbits)
{
  __shared__ __bf16 lds[3][12288];  // per buf: A 64x64 (4096) + B 128x64 (8192)

  const int tid  = threadIdx.x;
  const int lane = tid & 63;
  const int wid  = tid >> 6;         // 0..7
  const int wm   = wid >> 2, wn = wid & 3;
  const int fr   = lane & 15, fk = lane >> 4;

  const int cpx  = gridDim.x >> 3;
  const int wgid = (blockIdx.x & 7) * cpx + (blockIdx.x >> 3);
  const int bx   = wgid & ((1 << bxbits) - 1);
  const int by   = wgid >> bxbits;
  const int bn0  = bx * 128, bm0 = by * 64;

  // staging: row = tid>>3 (0..63), slot = tid&7 (linear dest).
  // Source k-chunk pre-swizzled: ko = slot ^ (row&7).
  const int srow = tid >> 3;
  const int sko  = ((tid & 7) ^ (srow & 7)) << 3;  // elems
  const __bf16* a0p = A + (size_t)(bm0 + srow) * LDF + sko;
  const __bf16* b0p = W + (size_t)(bn0 + srow) * Kd + sko;
  const __bf16* b1p = b0p + (size_t)64 * Kd;

#define STAGE(b, kt) do {                                            \
    async16((void*)(&lds[b][(size_t)tid * 8]),          a0p + (kt)); \
    async16((void*)(&lds[b][(size_t)(4096 + tid * 8)]), b0p + (kt)); \
    async16((void*)(&lds[b][(size_t)(8192 + tid * 8)]), b1p + (kt)); \
  } while (0)

  // fragment read offsets (loop-invariant): elem = r*64 + ((kc ^ (r&7))<<3)
  int aoff[2][2], boff[2][2];
#pragma unroll
  for (int ksub = 0; ksub < 2; ++ksub) {
    const int kc = ksub * 4 + fk;
#pragma unroll
    for (int i = 0; i < 2; ++i) {
      int ra = wm * 32 + i * 16 + fr;
      aoff[ksub][i] = ra * 64 + ((kc ^ (ra & 7)) << 3);
      int rb2 = wn * 32 + i * 16 + fr;
      boff[ksub][i] = 4096 + rb2 * 64 + ((kc ^ (rb2 & 7)) << 3);
    }
  }

  f32x4 acc[2][2] = {};

  const int NT = Kd >> 6;
  STAGE(0, 0);
  STAGE(1, 64);

  int rb = 0;
  for (int t = 0; t < NT; ++t) {
    if (t < NT - 1) asm volatile("s_waitcnt vmcnt(3)" ::: "memory");
    else            asm volatile("s_waitcnt vmcnt(0)" ::: "memory");
    __builtin_amdgcn_s_barrier();
    __builtin_amdgcn_sched_barrier(0);

    if (t + 2 < NT) {
      int sb = rb + 2; if (sb >= 3) sb -= 3;
      STAGE(sb, (t + 2) * 64);
    }
    __builtin_amdgcn_sched_barrier(0);

    const __bf16* bp = lds[rb];
#pragma unroll
    for (int ksub = 0; ksub < 2; ++ksub) {
      bf16x8 af[2], bf[2];
#pragma unroll
      for (int i = 0; i < 2; ++i) {
        af[i] = *(const bf16x8*)(bp + aoff[ksub][i]);
        bf[i] = *(const bf16x8*)(bp + boff[ksub][i]);
      }
#pragma unroll
      for (int mi = 0; mi < 2; ++mi)
#pragma unroll
        for (int ni = 0; ni < 2; ++ni)
          acc[mi][ni] = __builtin_amdgcn_mfma_f32_16x16x32_bf16(af[mi], bf[ni], acc[mi][ni], 0, 0, 0);
    }

    if (++rb == 3) rb = 0;
  }
#undef STAGE

  if (mode) {
    float psum[2] = {0.f, 0.f}, psq[2] = {0.f, 0.f};
#pragma unroll
    for (int mi = 0; mi < 2; ++mi) {
#pragma unroll
      for (int ni = 0; ni < 2; ++ni) {
        const int col  = bn0 + wn * 32 + ni * 16 + fr;
        const int row0 = bm0 + wm * 32 + mi * 16 + fk * 4;
        const float bv = badj[col];
        __bf16* hp = hout + (size_t)row0 * LDF + col;
#pragma unroll
        for (int r = 0; r < 4; ++r) {
          float v = fmaxf(acc[mi][ni][r] + bv, 0.f);
          psum[ni] += v; psq[ni] += v * v;
          hp[(size_t)r * LDF] = (__bf16)v;
        }
      }
    }
#pragma unroll
    for (int ni = 0; ni < 2; ++ni) {
      float s = psum[ni], q = psq[ni];
      s += __shfl_xor(s, 16); s += __shfl_xor(s, 32);
      q += __shfl_xor(q, 16); q += __shfl_xor(q, 32);
      if (fk == 0) {
        int col = bn0 + wn * 32 + ni * 16 + fr;
        atomicAdd(&colsum[col], s);
        atomicAdd(&colsumsq[col], q);
      }
    }
  } else {
#pragma unroll
    for (int mi = 0; mi < 2; ++mi) {
#pragma unroll
      for (int ni = 0; ni < 2; ++ni) {
        const int col  = bn0 + wn * 32 + ni * 16 + fr;
        const int row0 = bm0 + wm * 32 + mi * 16 + fk * 4;
        const float bv = badj[col];
        float* cp = fout + (size_t)row0 * 128 + col;
#pragma unroll
        for (int r = 0; r < 4; ++r)
          cp[(size_t)r * 128] = acc[mi][ni][r] + bv;
      }
    }
  }
}

__global__ void cast_x_kernel(const float* __restrict__ x, __bf16* __restrict__ feats) {
  int idx = blockIdx.x * blockDim.x + threadIdx.x;  // B_ROWS*64 threads
  int row = idx >> 6, c8 = (idx & 63) << 3;
  const float4* xp = (const float4*)(x + (size_t)row * 512 + c8);
  float4 a = xp[0], b = xp[1];
  *(bf16x8*)(feats + (size_t)row * LDF + c8) = cvt8(a, b);
}

// Fused fp32->bf16 W-cast with BN folded: W'[n,c]=W[n,c]*sc[c]; badj[n]=bias[n]+sum_c sh[c]*W[n,c]
// Also zeroes this stage's colsum/colsumsq slice (256 entries) if zs/zq given.
__global__ void prep_w(const float* __restrict__ W, const float* __restrict__ bias,
                       const float* __restrict__ colsum, const float* __restrict__ colsumsq,
                       const float* __restrict__ gamma, const float* __restrict__ beta,
                       __bf16* __restrict__ Wb, float* __restrict__ badj, int Kd,
                       float* __restrict__ zs, float* __restrict__ zq)
{
  const int n = blockIdx.x, t = threadIdx.x;  // 256 threads per row
  if (zs && t == 0 && n < 256) { zs[n] = 0.f; zq[n] = 0.f; }
  const float invB = 1.0f / 16384.0f;
  float accb = 0.f;
  for (int c0 = t * 4; c0 < Kd; c0 += 1024) {
    float4 w = *(const float4*)(W + (size_t)n * Kd + c0);
    float wv[4] = {w.x, w.y, w.z, w.w};
    bf16x4 o;
#pragma unroll
    for (int i = 0; i < 4; ++i) {
      int c = c0 + i;
      float sc = 1.f, sh = 0.f;
      if (c >= 512) {
        int idx = c - 512;
        float mu  = colsum[idx] * invB;
        float var = colsumsq[idx] * invB - mu * mu;
        sc = gamma[idx] * rsqrtf(var + BN_EPS);
        sh = beta[idx] - mu * sc;
      }
      accb += wv[i] * sh;
      o[i] = (__bf16)(wv[i] * sc);
    }
    *(bf16x4*)(Wb + (size_t)n * Kd + c0) = o;
  }
  __shared__ float red[256];
  red[t] = accb;
  __syncthreads();
  for (int s = 128; s > 0; s >>= 1) {
    if (t < s) red[t] += red[t + s];
    __syncthreads();
  }
  if (t == 0) badj[n] = bias[n] + red[0];
}

extern "C" void kernel_launch(void* const* d_in, const int* in_sizes, int n_in,
                              void* d_out, int out_size, void* d_ws, size_t ws_size,
                              hipStream_t stream) {
  const float* x = (const float*)d_in[0];
  const float* Wi[8];
  for (int i = 0; i < 8; ++i) Wi[i] = (const float*)d_in[1 + i];
  const float* b     = (const float*)d_in[9];
  const float* gamma = (const float*)d_in[10];
  const float* beta  = (const float*)d_in[11];
  const float* Wout  = (const float*)d_in[12];
  const float* bout  = (const float*)d_in[13];
  float* out = (float*)d_out;

  char* ws = (char*)d_ws;
  __bf16* feats = (__bf16*)ws;
  size_t off = (size_t)B_ROWS * LDF * 2;
  __bf16* wb[8];
  {
    int d = 512;
    for (int i = 0; i < 8; ++i) { wb[i] = (__bf16*)(ws + off); off += (size_t)256 * d * 2; d += 256; }
  }
  __bf16* woutb = (__bf16*)(ws + off); off += (size_t)128 * 2560 * 2;
  float* colsum   = (float*)(ws + off); off += 8 * 256 * 4;
  float* colsumsq = (float*)(ws + off); off += 8 * 256 * 4;
  float* badj     = (float*)(ws + off); off += 9 * 256 * 4;

  cast_x_kernel<<<B_ROWS * 64 / 256, 256, 0, stream>>>(x, feats);

  int d = 512;
  for (int i = 0; i < 8; ++i) {
    prep_w<<<256, 256, 0, stream>>>(Wi[i], b + i * 256, colsum, colsumsq,
                                    gamma, beta, wb[i], badj + i * 256, d,
                                    colsum + i * 256, colsumsq + i * 256);
    // grid = 2 bx * 256 by = 512 blocks of 512 threads (16 waves/CU)
    gemm_stage<<<512, 512, 0, stream>>>(feats, wb[i], badj + i * 256,
                                        feats + d, nullptr,
                                        colsum + i * 256, colsumsq + i * 256,
                                        d, 1, 1);
    d += 256;
  }
  prep_w<<<128, 256, 0, stream>>>(Wout, bout, colsum, colsumsq,
                                  gamma, beta, woutb, badj + 8 * 256, 2560,
                                  nullptr, nullptr);
  // final: direct (no split-K): grid = 1 bx * 256 by = 256 blocks, NT=40
  gemm_stage<<<256, 512, 0, stream>>>(feats, woutb, badj + 8 * 256,
                                      nullptr, out, nullptr, nullptr,
                                      2560, 0, 0);
}

// Round 18
// 275.428 us; speedup vs baseline: 1.0969x; 1.0242x over previous
//
#include <hip/hip_runtime.h>
#include <hip/hip_bf16.h>

typedef __attribute__((ext_vector_type(8))) __bf16 bf16x8;
typedef __attribute__((ext_vector_type(4))) __bf16 bf16x4;
typedef __attribute__((ext_vector_type(4))) float f32x4;

#define B_ROWS 16384
#define LDF 2560
#define BN_EPS 1e-5f

__device__ __forceinline__ void async16(void* lds, const void* g) {
  __builtin_amdgcn_global_load_lds(
      (const __attribute__((address_space(1))) unsigned int*)g,
      (__attribute__((address_space(3))) unsigned int*)lds, 16, 0, 0);
}

__device__ __forceinline__ bf16x8 cvt8(float4 a, float4 b) {
  bf16x8 t;
  t[0] = (__bf16)a.x; t[1] = (__bf16)a.y; t[2] = (__bf16)a.z; t[3] = (__bf16)a.w;
  t[4] = (__bf16)b.x; t[5] = (__bf16)b.y; t[6] = (__bf16)b.z; t[7] = (__bf16)b.w;
  return t;
}

// C-tile = A(bf16,[B_ROWS,LDF]) x W(bf16,[Ntot,Kd])^T (+badj in epilogue)
// BM=64 x BN=128, BK=64, 512 threads = 8 waves (2wm x 4wn), wave-tile 32x32,
// acc 2x2. 16 waves/CU at 2 blocks/CU (72KB LDS). [R13/R15/R17-verified;
// stage-7 time == LDS-pipe floor: 2 blk x 88KB/iter / 128 B/cyc x NT=36.
// Tile family is optimal: reads/iter = nwaves*(Tm+Tn)*BK minimized at Tm=Tn=32
// subject to 512 thr + 2 blk/CU (BMxBN>=128^2 forces grid 256 = 1/CU, R16 regress).]
// 3-buffer LDS, prefetch depth 2. STAGE = 3 gload_lds/thread; loop top has
// tiles t,t+1 in flight (6/thread); vmcnt(3) completes exactly tile t.
// LDS row = 64 elems (8 slots of 8); slot holds k-chunk (slot ^ (row&7)) via
// pre-swizzled source; read slot = kc ^ (row&7) -> 2 lanes/bank (free).
// Grid 1-D, XCD-chunked swizzle (gridDim%8==0): wgid -> (bx, by).
// mode 1: h=relu(acc+badj) -> bf16 hout (stride LDF) + col stats atomics.
// mode 0: fp32 out = acc + badj (ldc=128), direct (no split-K).
__global__ __launch_bounds__(512) void gemm_stage(
    const __bf16* __restrict__ A, const __bf16* __restrict__ W,
    const float* __restrict__ badj,
    __bf16* __restrict__ hout, float* __restrict__ fout,
    float* __restrict__ colsum, float* __restrict__ colsumsq,
    int Kd, int mode, int bxbits)
{
  __shared__ __bf16 lds[3][12288];  // per buf: A 64x64 (4096) + B 128x64 (8192)

  const int tid  = threadIdx.x;
  const int lane = tid & 63;
  const int wid  = tid >> 6;         // 0..7
  const int wm   = wid >> 2, wn = wid & 3;
  const int fr   = lane & 15, fk = lane >> 4;

  const int cpx  = gridDim.x >> 3;
  const int wgid = (blockIdx.x & 7) * cpx + (blockIdx.x >> 3);
  const int bx   = wgid & ((1 << bxbits) - 1);
  const int by   = wgid >> bxbits;
  const int bn0  = bx * 128, bm0 = by * 64;

  // staging: row = tid>>3 (0..63), slot = tid&7 (linear dest).
  // Source k-chunk pre-swizzled: ko = slot ^ (row&7).
  const int srow = tid >> 3;
  const int sko  = ((tid & 7) ^ (srow & 7)) << 3;  // elems
  const __bf16* a0p = A + (size_t)(bm0 + srow) * LDF + sko;
  const __bf16* b0p = W + (size_t)(bn0 + srow) * Kd + sko;
  const __bf16* b1p = b0p + (size_t)64 * Kd;

#define STAGE(b, kt) do {                                            \
    async16((void*)(&lds[b][(size_t)tid * 8]),          a0p + (kt)); \
    async16((void*)(&lds[b][(size_t)(4096 + tid * 8)]), b0p + (kt)); \
    async16((void*)(&lds[b][(size_t)(8192 + tid * 8)]), b1p + (kt)); \
  } while (0)

  // fragment read offsets (loop-invariant): elem = r*64 + ((kc ^ (r&7))<<3)
  int aoff[2][2], boff[2][2];
#pragma unroll
  for (int ksub = 0; ksub < 2; ++ksub) {
    const int kc = ksub * 4 + fk;
#pragma unroll
    for (int i = 0; i < 2; ++i) {
      int ra = wm * 32 + i * 16 + fr;
      aoff[ksub][i] = ra * 64 + ((kc ^ (ra & 7)) << 3);
      int rb2 = wn * 32 + i * 16 + fr;
      boff[ksub][i] = 4096 + rb2 * 64 + ((kc ^ (rb2 & 7)) << 3);
    }
  }

  f32x4 acc[2][2] = {};

  const int NT = Kd >> 6;
  STAGE(0, 0);
  STAGE(1, 64);

  int rb = 0;
  for (int t = 0; t < NT; ++t) {
    if (t < NT - 1) asm volatile("s_waitcnt vmcnt(3)" ::: "memory");
    else            asm volatile("s_waitcnt vmcnt(0)" ::: "memory");
    __builtin_amdgcn_s_barrier();
    __builtin_amdgcn_sched_barrier(0);

    if (t + 2 < NT) {
      int sb = rb + 2; if (sb >= 3) sb -= 3;
      STAGE(sb, (t + 2) * 64);
    }
    __builtin_amdgcn_sched_barrier(0);

    const __bf16* bp = lds[rb];
#pragma unroll
    for (int ksub = 0; ksub < 2; ++ksub) {
      bf16x8 af[2], bf[2];
#pragma unroll
      for (int i = 0; i < 2; ++i) {
        af[i] = *(const bf16x8*)(bp + aoff[ksub][i]);
        bf[i] = *(const bf16x8*)(bp + boff[ksub][i]);
      }
#pragma unroll
      for (int mi = 0; mi < 2; ++mi)
#pragma unroll
        for (int ni = 0; ni < 2; ++ni)
          acc[mi][ni] = __builtin_amdgcn_mfma_f32_16x16x32_bf16(af[mi], bf[ni], acc[mi][ni], 0, 0, 0);
    }

    if (++rb == 3) rb = 0;
  }
#undef STAGE

  if (mode) {
    float psum[2] = {0.f, 0.f}, psq[2] = {0.f, 0.f};
#pragma unroll
    for (int mi = 0; mi < 2; ++mi) {
#pragma unroll
      for (int ni = 0; ni < 2; ++ni) {
        const int col  = bn0 + wn * 32 + ni * 16 + fr;
        const int row0 = bm0 + wm * 32 + mi * 16 + fk * 4;
        const float bv = badj[col];
        __bf16* hp = hout + (size_t)row0 * LDF + col;
#pragma unroll
        for (int r = 0; r < 4; ++r) {
          float v = fmaxf(acc[mi][ni][r] + bv, 0.f);
          psum[ni] += v; psq[ni] += v * v;
          hp[(size_t)r * LDF] = (__bf16)v;
        }
      }
    }
#pragma unroll
    for (int ni = 0; ni < 2; ++ni) {
      float s = psum[ni], q = psq[ni];
      s += __shfl_xor(s, 16); s += __shfl_xor(s, 32);
      q += __shfl_xor(q, 16); q += __shfl_xor(q, 32);
      if (fk == 0) {
        int col = bn0 + wn * 32 + ni * 16 + fr;
        atomicAdd(&colsum[col], s);
        atomicAdd(&colsumsq[col], q);
      }
    }
  } else {
#pragma unroll
    for (int mi = 0; mi < 2; ++mi) {
#pragma unroll
      for (int ni = 0; ni < 2; ++ni) {
        const int col  = bn0 + wn * 32 + ni * 16 + fr;
        const int row0 = bm0 + wm * 32 + mi * 16 + fk * 4;
        const float bv = badj[col];
        float* cp = fout + (size_t)row0 * 128 + col;
#pragma unroll
        for (int r = 0; r < 4; ++r)
          cp[(size_t)r * 128] = acc[mi][ni][r] + bv;
      }
    }
  }
}

// Fused fp32->bf16 W-cast with BN folded: W'[n,c]=W[n,c]*sc[c];
// badj[n]=bias[n]+sum_c sh[c]*W[n,c]. Blocks >= nW do x->bf16 cast instead
// (stage-0 launch only): removes the separate cast_x dispatch.
// Also zeroes this stage's colsum/colsumsq slice (256 entries) if zs/zq given.
__global__ __launch_bounds__(256) void prep_w(
    const float* __restrict__ W, const float* __restrict__ bias,
    const float* __restrict__ colsum, const float* __restrict__ colsumsq,
    const float* __restrict__ gamma, const float* __restrict__ beta,
    __bf16* __restrict__ Wb, float* __restrict__ badj, int Kd,
    float* __restrict__ zs, float* __restrict__ zq,
    const float* __restrict__ x, __bf16* __restrict__ xout, int nW)
{
  const int blk = blockIdx.x, t = threadIdx.x;
  if (blk >= nW) {
    // cast region: 4096 blocks x 256 threads, 8 elems each
    int idx = (blk - nW) * 256 + t;
    int row = idx >> 6, c8 = (idx & 63) << 3;
    const float4* xp = (const float4*)(x + (size_t)row * 512 + c8);
    float4 a = xp[0], b2 = xp[1];
    *(bf16x8*)(xout + (size_t)row * LDF + c8) = cvt8(a, b2);
    return;
  }
  const int n = blk;
  if (zs && t == 0) { zs[n] = 0.f; zq[n] = 0.f; }
  const float invB = 1.0f / 16384.0f;
  float accb = 0.f;
  for (int c0 = t * 4; c0 < Kd; c0 += 1024) {
    float4 w = *(const float4*)(W + (size_t)n * Kd + c0);
    float wv[4] = {w.x, w.y, w.z, w.w};
    bf16x4 o;
#pragma unroll
    for (int i = 0; i < 4; ++i) {
      int c = c0 + i;
      float sc = 1.f, sh = 0.f;
      if (c >= 512) {
        int idx = c - 512;
        float mu  = colsum[idx] * invB;
        float var = colsumsq[idx] * invB - mu * mu;
        sc = gamma[idx] * rsqrtf(var + BN_EPS);
        sh = beta[idx] - mu * sc;
      }
      accb += wv[i] * sh;
      o[i] = (__bf16)(wv[i] * sc);
    }
    *(bf16x4*)(Wb + (size_t)n * Kd + c0) = o;
  }
  // wave shuffle reduce (64-wide) + tiny cross-wave LDS combine
  float s = accb;
  s += __shfl_xor(s, 1);  s += __shfl_xor(s, 2);  s += __shfl_xor(s, 4);
  s += __shfl_xor(s, 8);  s += __shfl_xor(s, 16); s += __shfl_xor(s, 32);
  __shared__ float wred[4];
  if ((t & 63) == 0) wred[t >> 6] = s;
  __syncthreads();
  if (t == 0) badj[n] = bias[n] + wred[0] + wred[1] + wred[2] + wred[3];
}

extern "C" void kernel_launch(void* const* d_in, const int* in_sizes, int n_in,
                              void* d_out, int out_size, void* d_ws, size_t ws_size,
                              hipStream_t stream) {
  const float* x = (const float*)d_in[0];
  const float* Wi[8];
  for (int i = 0; i < 8; ++i) Wi[i] = (const float*)d_in[1 + i];
  const float* b     = (const float*)d_in[9];
  const float* gamma = (const float*)d_in[10];
  const float* beta  = (const float*)d_in[11];
  const float* Wout  = (const float*)d_in[12];
  const float* bout  = (const float*)d_in[13];
  float* out = (float*)d_out;

  char* ws = (char*)d_ws;
  __bf16* feats = (__bf16*)ws;
  size_t off = (size_t)B_ROWS * LDF * 2;
  __bf16* wb[8];
  {
    int d = 512;
    for (int i = 0; i < 8; ++i) { wb[i] = (__bf16*)(ws + off); off += (size_t)256 * d * 2; d += 256; }
  }
  __bf16* woutb = (__bf16*)(ws + off); off += (size_t)128 * 2560 * 2;
  float* colsum   = (float*)(ws + off); off += 8 * 256 * 4;
  float* colsumsq = (float*)(ws + off); off += 8 * 256 * 4;
  float* badj     = (float*)(ws + off); off += 9 * 256 * 4;

  int d = 512;
  for (int i = 0; i < 8; ++i) {
    if (i == 0) {
      // prep_w (256 blocks) + x->bf16 cast (4096 blocks) fused in one launch
      prep_w<<<256 + 4096, 256, 0, stream>>>(Wi[0], b, colsum, colsumsq,
                                             gamma, beta, wb[0], badj, d,
                                             colsum, colsumsq,
                                             x, feats, 256);
    } else {
      prep_w<<<256, 256, 0, stream>>>(Wi[i], b + i * 256, colsum, colsumsq,
                                      gamma, beta, wb[i], badj + i * 256, d,
                                      colsum + i * 256, colsumsq + i * 256,
                                      nullptr, nullptr, 256);
    }
    // grid = 2 bx * 256 by = 512 blocks of 512 threads (16 waves/CU)
    gemm_stage<<<512, 512, 0, stream>>>(feats, wb[i], badj + i * 256,
                                        feats + d, nullptr,
                                        colsum + i * 256, colsumsq + i * 256,
                                        d, 1, 1);
    d += 256;
  }
  prep_w<<<128, 256, 0, stream>>>(Wout, bout, colsum, colsumsq,
                                  gamma, beta, woutb, badj + 8 * 256, 2560,
                                  nullptr, nullptr, nullptr, nullptr, 128);
  // final: direct (no split-K): grid = 1 bx * 256 by = 256 blocks, NT=40
  gemm_stage<<<256, 512, 0, stream>>>(feats, woutb, badj + 8 * 256,
                                      nullptr, out, nullptr, nullptr,
                                      2560, 0, 0);
}